// Round 10
// baseline (1218.207 us; speedup 1.0000x reference)
//
#include <hip/hip_runtime.h>
#include <math.h>

#define Hdim 2048
#define Ldim 256
#define NBLK 256
#define TPB  1024
#define JPB  8      // h-elements per block (Hdim / NBLK)
#define NREP 8      // replicas (consumers shard by b&7)

typedef unsigned long long u64;
typedef int i32x4 __attribute__((ext_vector_type(4)));

// ws layout (u32 units from hq):
//   hq[0 .. 2*NREP*2048)          payload: [parity][rep][2048] packed words
//       word = (f32 bits & 0xFFFFFF00) | step_tag8   (tag in mantissa low byte)
//   sq = hq + 2*NREP*2048;  sq[rep*256 + b] = highest step published by block b
//       (monotone int; harness 0xAA poison is negative -> "not ready")
#define PAYLOAD_WORDS (2*NREP*Hdim)

// 16B coherent load (bypasses L1/L2, reads the coherence point)
__device__ __forceinline__ i32x4 ld16_cohr(const int* p) {
    i32x4 v;
    asm volatile("global_load_dwordx4 %0, %1, off sc0 sc1\n\t"
                 "s_waitcnt vmcnt(0)"
                 : "=v"(v) : "v"(p) : "memory");
    return v;
}

// ---------------- single fused persistent kernel ----------------------------
// 256 blocks x 1024 threads, 1 block/CU. Block b owns h[j], j = b*8..b*8+7.
// Two-phase sync: (1) ONLY wave0 polls the 256-summary-tag array (64
// outstanding loads/block vs 1024 -> Little's-law latency collapse);
// (2) after B0, each thread does ONE 8B payload load, verified by the
// embedded mantissa tags (handles payload/summary store reordering).
__global__ __launch_bounds__(TPB, 4) void gru_all(
    const float* __restrict__ Whh,  const float* __restrict__ bhh,
    const float* __restrict__ Wout, const float* __restrict__ bout,
    const float* __restrict__ tps,  const float* __restrict__ pkdata,
    const int*   __restrict__ tf,   const float* __restrict__ smiles,
    const float* __restrict__ Wp,   const float* __restrict__ bpre,
    const float* __restrict__ Wih,  const float* __restrict__ bih,
    const float* __restrict__ dose, const float* __restrict__ route,
    const float* __restrict__ emb,  const int* __restrict__ pat,
    float* __restrict__ ws, float* __restrict__ out)
{
    const int b    = blockIdx.x;
    const int tid  = threadIdx.x;
    const int k    = tid & 127;     // column group within j (dots)
    const int g    = tid >> 7;      // which j this thread's dot serves
    const int wv   = tid >> 6;      // wave id 0..15
    const int lane = tid & 63;
    const int j    = b*JPB + g;
    const int rep  = b & 7;         // this block's replica shard

    __shared__ float su[Hdim];      // u vector (prep only)
    __shared__ float sh_h[Hdim];
    __shared__ float sred[16][3];
    __shared__ float swp[2][16];
    __shared__ float sA[24], sT[24], sC[24];
    __shared__ float s_tp[Ldim];
    __shared__ float s_pkd[Ldim];
    __shared__ int   s_tf[Ldim];

    unsigned* hq = (unsigned*)ws;
    int*      sq = (int*)(hq + PAYLOAD_WORDS);

    // small per-step scalars
    for (int i = tid; i < Ldim; i += TPB) {
        s_tp[i]  = tps[i];
        s_pkd[i] = pkdata[i];
        s_tf[i]  = tf[i];
    }

    // ---- prep A: u[i] = Wp[i,2:7].consts + b_pre[i] into LDS ----
    {
        float d = dose[0], rt = route[0];
        int p = pat[0];
        float e0 = emb[p*3+0], e1 = emb[p*3+1], e2 = emb[p*3+2];
        for (int i = tid; i < Hdim; i += TPB) {
            const float* wr = Wp + i*7;
            su[i] = d*wr[2] + e0*wr[3] + e1*wr[4] + e2*wr[5] + rt*wr[6] + bpre[i];
        }
    }

    // W_hh rows -> registers (48 VGPRs), coalesced float4 loads
    float4 w[3][4];
    #pragma unroll
    for (int r = 0; r < 3; ++r) {
        const float* base = Whh + (size_t)(j + r*Hdim) * Hdim;
        #pragma unroll
        for (int c = 0; c < 4; ++c)
            w[r][c] = *(const float4*)(base + c*512 + k*4);
    }

    // per-thread W_out slice
    const int i0 = tid * 2;
    const float wo0 = Wout[i0], wo1 = Wout[i0 + 1];
    const float bo = bout[0];

    __syncthreads();   // su ready

    // ---- prep B: fold this block's 24 W_ih rows ----
    #pragma unroll
    for (int pass = 0; pass < 2; ++pass) {
        int ri = wv + pass*16;
        if (ri < 24) {
            int grow = (ri >> 3)*Hdim + b*JPB + (ri & 7);
            const float* wr = Wih + (size_t)grow * Hdim;
            float s0 = 0.f, s1 = 0.f, s2 = 0.f;
            #pragma unroll
            for (int c = 0; c < 8; ++c) {
                int col = c*256 + lane*4;
                float4 wv4 = *(const float4*)(wr + col);
                float4 uv4 = *(const float4*)(su + col);
                s0 += wv4.x*Wp[(col+0)*7+0] + wv4.y*Wp[(col+1)*7+0]
                    + wv4.z*Wp[(col+2)*7+0] + wv4.w*Wp[(col+3)*7+0];
                s1 += wv4.x*Wp[(col+0)*7+1] + wv4.y*Wp[(col+1)*7+1]
                    + wv4.z*Wp[(col+2)*7+1] + wv4.w*Wp[(col+3)*7+1];
                s2 += wv4.x*uv4.x + wv4.y*uv4.y + wv4.z*uv4.z + wv4.w*uv4.w;
            }
            #pragma unroll
            for (int off = 32; off >= 1; off >>= 1) {
                s0 += __shfl_down(s0, off, 64);
                s1 += __shfl_down(s1, off, 64);
                s2 += __shfl_down(s2, off, 64);
            }
            if (lane == 0) {
                sA[ri] = s0;
                sT[ri] = s1;
                sC[ri] = s2 + bih[grow];
            }
        }
    }
    __syncthreads();   // sA/sT/sC ready

    // ---- wave0: gate constants + replicated tagged h0 publish + summary ----
    float apk_r=0, apk_z=0, apk_n=0, atp_r=0, atp_z=0, atp_n=0,
          cvt_r=0, cvt_z=0, cvt_n=0, br=0, bz=0, bn=0, hprev=0;
    if (wv == 0) {
        float hinit = 0.f;
        if (lane < JPB) {
            int jj = b*JPB + lane;
            apk_r = sA[lane]; apk_z = sA[8+lane]; apk_n = sA[16+lane];
            atp_r = sT[lane]; atp_z = sT[8+lane]; atp_n = sT[16+lane];
            cvt_r = sC[lane]; cvt_z = sC[8+lane]; cvt_n = sC[16+lane];
            br = bhh[jj]; bz = bhh[jj + Hdim]; bn = bhh[jj + 2*Hdim];
            hprev = smiles[jj];
            hinit = hprev;
        }
        // payload: one wave-store covers all 8 replicas (tag 0)
        float hv = __shfl(hinit, lane & 7);
        unsigned w0 = (__float_as_uint(hv) & 0xFFFFFF00u);
        __hip_atomic_store(hq + (size_t)(lane >> 3)*Hdim + b*JPB + (lane & 7), w0,
                           __ATOMIC_RELAXED, __HIP_MEMORY_SCOPE_AGENT);
        // summary: lanes 0..7 -> 8 replica arrays
        if (lane < NREP)
            __hip_atomic_store(sq + lane*256 + b, 0,
                               __ATOMIC_RELAXED, __HIP_MEMORY_SCOPE_AGENT);
        if (b == 0 && lane == 0) out[0] = pkdata[0];
    }

    // ================== main recurrence loop ==================
    for (int t = 0; t < Ldim - 1; ++t) {
        const int pr_ = t & 1;
        const unsigned* hin = hq + (size_t)(pr_*NREP + rep)*Hdim;
        const unsigned tt = (unsigned)t & 0xFFu;

        // ---- phase 1: wave0 polls the 256 summary tags (1 dwordx4/lane) ----
        if (wv == 0) {
            const int* sp = sq + rep*256 + lane*4;
            for (;;) {
                i32x4 s4 = ld16_cohr(sp);
                if (__all(s4.x >= t && s4.y >= t && s4.z >= t && s4.w >= t)) break;
            }
        }
        __syncthreads();                         // B0: step t fully published

        // ---- phase 2: one-shot 8B payload load, verify embedded tags ----
        u64 q;
        for (;;) {
            q = __hip_atomic_load((const u64*)(hin + i0),
                                  __ATOMIC_RELAXED, __HIP_MEMORY_SCOPE_AGENT);
            if (((unsigned)q & 0xFFu) == tt &&
                ((unsigned)(q >> 32) & 0xFFu) == tt) break;
        }
        float h0 = __uint_as_float((unsigned)q         & 0xFFFFFF00u);
        float h1 = __uint_as_float((unsigned)(q >> 32) & 0xFFFFFF00u);
        sh_h[i0]     = h0;
        sh_h[i0 + 1] = h1;

        // local pred partial (pred_{t-1} = W_out . h_t + b_out)
        float wpart = wo0*h0 + wo1*h1;
        #pragma unroll
        for (int off = 32; off >= 1; off >>= 1) wpart += __shfl_down(wpart, off, 64);
        if (lane == 0) swp[pr_][wv] = wpart;
        __syncthreads();                         // B1: h staged

        // ---- dots: 3 gate rows x 16 columns per thread, from LDS ----
        float prd = 0.f, pzd = 0.f, pnd = 0.f;
        #pragma unroll
        for (int c = 0; c < 4; ++c) {
            float4 hv4 = *(const float4*)(sh_h + c*512 + k*4);
            prd += w[0][c].x*hv4.x + w[0][c].y*hv4.y + w[0][c].z*hv4.z + w[0][c].w*hv4.w;
            pzd += w[1][c].x*hv4.x + w[1][c].y*hv4.y + w[1][c].z*hv4.z + w[1][c].w*hv4.w;
            pnd += w[2][c].x*hv4.x + w[2][c].y*hv4.y + w[2][c].z*hv4.z + w[2][c].w*hv4.w;
        }
        #pragma unroll
        for (int off = 32; off >= 1; off >>= 1) {
            prd += __shfl_down(prd, off, 64);
            pzd += __shfl_down(pzd, off, 64);
            pnd += __shfl_down(pnd, off, 64);
        }
        if (lane == 0) { sred[wv][0] = prd; sred[wv][1] = pzd; sred[wv][2] = pnd; }
        __syncthreads();                         // B2: sred ready

        // ---- wave 0: pred, pk, gates, replicated publish + summary ----
        if (wv == 0) {
            float s = (lane < 16) ? swp[pr_][lane] : 0.f;
            s += __shfl_down(s, 8, 64);
            s += __shfl_down(s, 4, 64);
            s += __shfl_down(s, 2, 64);
            s += __shfl_down(s, 1, 64);
            float pred = __shfl(s, 0) + bo;      // pred_{t-1}
            float pk = (t == 0) ? s_pkd[0] : ((s_tf[t] == 1) ? pred : s_pkd[t]);
            if (b == 0 && lane == 0 && t > 0) out[t] = pred;
            float hvnew = 0.f;
            if (lane < JPB) {
                float dotr = sred[2*lane][0] + sred[2*lane+1][0];
                float dotz = sred[2*lane][1] + sred[2*lane+1][1];
                float dotn = sred[2*lane][2] + sred[2*lane+1][2];
                float tp  = s_tp[t];
                float gr  = apk_r*pk + atp_r*tp + cvt_r + dotr + br;
                float gz  = apk_z*pk + atp_z*tp + cvt_z + dotz + bz;
                float gin = apk_n*pk + atp_n*tp + cvt_n;
                float r = 1.0f / (1.0f + expf(-gr));
                float z = 1.0f / (1.0f + expf(-gz));
                float n = tanhf(gin + r*(dotn + bn));
                hvnew = (1.0f - z)*n + z*hprev;
                hprev = hvnew;
            }
            // payload to all 8 replicas (one wave-store), then summary tags
            float hv = __shfl(hvnew, lane & 7);
            unsigned wpk = (__float_as_uint(hv) & 0xFFFFFF00u)
                         | ((unsigned)(t + 1) & 0xFFu);
            __hip_atomic_store(hq + (size_t)(((pr_^1)*NREP) + (lane >> 3))*Hdim
                                   + b*JPB + (lane & 7), wpk,
                               __ATOMIC_RELAXED, __HIP_MEMORY_SCOPE_AGENT);
            if (lane < NREP)
                __hip_atomic_store(sq + lane*256 + b, t + 1,
                                   __ATOMIC_RELAXED, __HIP_MEMORY_SCOPE_AGENT);
        }
    }

    // ---- final: block 0 gathers h_255, writes out[255] ----
    if (b == 0) {
        const int tF = Ldim - 1;
        if (wv == 0) {
            const int* sp = sq + 0*256 + lane*4;   // block 0 -> replica 0
            for (;;) {
                i32x4 s4 = ld16_cohr(sp);
                if (__all(s4.x >= tF && s4.y >= tF && s4.z >= tF && s4.w >= tF)) break;
            }
        }
        __syncthreads();
        const unsigned* hin = hq + (size_t)((tF & 1)*NREP + 0)*Hdim;
        const unsigned tt = (unsigned)tF & 0xFFu;
        u64 q;
        for (;;) {
            q = __hip_atomic_load((const u64*)(hin + i0),
                                  __ATOMIC_RELAXED, __HIP_MEMORY_SCOPE_AGENT);
            if (((unsigned)q & 0xFFu) == tt &&
                ((unsigned)(q >> 32) & 0xFFu) == tt) break;
        }
        float h0 = __uint_as_float((unsigned)q         & 0xFFFFFF00u);
        float h1 = __uint_as_float((unsigned)(q >> 32) & 0xFFFFFF00u);
        float wpart = wo0*h0 + wo1*h1;
        #pragma unroll
        for (int off = 32; off >= 1; off >>= 1) wpart += __shfl_down(wpart, off, 64);
        if (lane == 0) swp[1][wv] = wpart;
        __syncthreads();
        if (wv == 0) {
            float s = (lane < 16) ? swp[1][lane] : 0.f;
            s += __shfl_down(s, 8, 64);
            s += __shfl_down(s, 4, 64);
            s += __shfl_down(s, 2, 64);
            s += __shfl_down(s, 1, 64);
            if (lane == 0) out[Ldim - 1] = s + bo;
        }
    }
}

extern "C" void kernel_launch(void* const* d_in, const int* in_sizes, int n_in,
                              void* d_out, int out_size, void* d_ws, size_t ws_size,
                              hipStream_t stream)
{
    const float* tps    = (const float*)d_in[0];   // timepoints (256,1)
    const float* pkdata = (const float*)d_in[1];   // pk_data (256,1)
    // d_in[2] = input_len (unused, static 256)
    const int*   pat    = (const int*)  d_in[3];   // emb_patient
    const float* route  = (const float*)d_in[4];   // drug_route (1,)
    const float* dose   = (const float*)d_in[5];   // dose (1,)
    const float* smiles = (const float*)d_in[6];   // (1, 2048)
    const int*   tfm    = (const int*)  d_in[7];   // tf_mask (256,)
    const float* emb    = (const float*)d_in[8];   // emb_table (8,3)
    const float* Wp     = (const float*)d_in[9];   // W_pre (2048,7)
    const float* bpre   = (const float*)d_in[10];  // b_pre (2048,)
    const float* Wih    = (const float*)d_in[11];  // W_ih (6144,2048)
    const float* Whh    = (const float*)d_in[12];  // W_hh (6144,2048)
    const float* bih    = (const float*)d_in[13];  // b_ih (6144,)
    const float* bhh    = (const float*)d_in[14];  // b_hh (6144,)
    const float* Wout   = (const float*)d_in[15];  // W_out (1,2048)
    const float* bout   = (const float*)d_in[16];  // b_out (1,)
    float* out = (float*)d_out;
    float* ws  = (float*)d_ws;

    hipLaunchKernelGGL(gru_all, dim3(NBLK), dim3(TPB), 0, stream,
                       Whh, bhh, Wout, bout, tps, pkdata, tfm, smiles,
                       Wp, bpre, Wih, bih, dose, route, emb, pat, ws, out);
}

// Round 11
// 1036.329 us; speedup vs baseline: 1.1755x; 1.1755x over previous
//
#include <hip/hip_runtime.h>
#include <math.h>

#define Hdim 2048
#define Ldim 256
#define NBLK 256
#define TPB  1024
#define JPB  8      // h-elements per block (Hdim / NBLK)

typedef unsigned long long u64;

// workspace: packed h buffer. 2 parities x 2048 u32 words.
// word = (f32 bits & 0xFFFFFF00) | step_tag8  — tag rides in the mantissa
// low byte (<=3e-5 relative perturbation). Detect = equality with t.
// Harness poisons ws with 0xAA -> low byte 0xAA, never equals tags 0/1
// before first write; stale slots hold tag t-2 != t. Race-free (2-phase).
#define WS_HP 0

// ---------------- single fused persistent kernel ----------------------------
// 256 blocks x 1024 threads, 1 block/CU. Block b owns h[j], j = b*8..b*8+7.
// r8 protocol (best minimal-serialization publish: ONE 32B line per producer)
// + s_sleep-throttled polling: failed poll iterations back off ~64 cyc,
// cutting the spin-issue storm that contends with the critical publish store
// on the CU memory port (and first-detect loads of the new step).
__global__ __launch_bounds__(TPB, 4) void gru_all(
    const float* __restrict__ Whh,  const float* __restrict__ bhh,
    const float* __restrict__ Wout, const float* __restrict__ bout,
    const float* __restrict__ tps,  const float* __restrict__ pkdata,
    const int*   __restrict__ tf,   const float* __restrict__ smiles,
    const float* __restrict__ Wp,   const float* __restrict__ bpre,
    const float* __restrict__ Wih,  const float* __restrict__ bih,
    const float* __restrict__ dose, const float* __restrict__ route,
    const float* __restrict__ emb,  const int* __restrict__ pat,
    float* __restrict__ ws, float* __restrict__ out)
{
    const int b    = blockIdx.x;
    const int tid  = threadIdx.x;
    const int k    = tid & 127;     // column group within j (dots)
    const int g    = tid >> 7;      // which j this thread's dot serves
    const int wv   = tid >> 6;      // wave id 0..15
    const int lane = tid & 63;
    const int j    = b*JPB + g;

    __shared__ float su[Hdim];      // u vector (prep only)
    __shared__ float sh_h[Hdim];
    __shared__ float sred[16][3];
    __shared__ float swp[2][16];
    __shared__ float sA[24], sT[24], sC[24];   // APK/ATP/CVT for own 24 rows
    __shared__ float s_tp[Ldim];
    __shared__ float s_pkd[Ldim];
    __shared__ int   s_tf[Ldim];

    unsigned* hq = (unsigned*)(ws + WS_HP);

    // small per-step scalars
    for (int i = tid; i < Ldim; i += TPB) {
        s_tp[i]  = tps[i];
        s_pkd[i] = pkdata[i];
        s_tf[i]  = tf[i];
    }

    // ---- prep A: u[i] = Wp[i,2:7].consts + b_pre[i] into LDS ----
    {
        float d = dose[0], rt = route[0];
        int p = pat[0];
        float e0 = emb[p*3+0], e1 = emb[p*3+1], e2 = emb[p*3+2];
        for (int i = tid; i < Hdim; i += TPB) {
            const float* wr = Wp + i*7;
            su[i] = d*wr[2] + e0*wr[3] + e1*wr[4] + e2*wr[5] + rt*wr[6] + bpre[i];
        }
    }

    // W_hh rows -> registers (48 VGPRs), coalesced float4 loads
    float4 w[3][4];
    #pragma unroll
    for (int r = 0; r < 3; ++r) {
        const float* base = Whh + (size_t)(j + r*Hdim) * Hdim;
        #pragma unroll
        for (int c = 0; c < 4; ++c)
            w[r][c] = *(const float4*)(base + c*512 + k*4);
    }

    // per-thread W_out slice
    const int i0 = tid * 2;
    const float wo0 = Wout[i0], wo1 = Wout[i0 + 1];
    const float bo = bout[0];

    __syncthreads();   // su ready

    // ---- prep B: fold this block's 24 W_ih rows ----
    #pragma unroll
    for (int pass = 0; pass < 2; ++pass) {
        int ri = wv + pass*16;
        if (ri < 24) {
            int grow = (ri >> 3)*Hdim + b*JPB + (ri & 7);
            const float* wr = Wih + (size_t)grow * Hdim;
            float s0 = 0.f, s1 = 0.f, s2 = 0.f;
            #pragma unroll
            for (int c = 0; c < 8; ++c) {
                int col = c*256 + lane*4;
                float4 wv4 = *(const float4*)(wr + col);
                float4 uv4 = *(const float4*)(su + col);
                s0 += wv4.x*Wp[(col+0)*7+0] + wv4.y*Wp[(col+1)*7+0]
                    + wv4.z*Wp[(col+2)*7+0] + wv4.w*Wp[(col+3)*7+0];
                s1 += wv4.x*Wp[(col+0)*7+1] + wv4.y*Wp[(col+1)*7+1]
                    + wv4.z*Wp[(col+2)*7+1] + wv4.w*Wp[(col+3)*7+1];
                s2 += wv4.x*uv4.x + wv4.y*uv4.y + wv4.z*uv4.z + wv4.w*uv4.w;
            }
            #pragma unroll
            for (int off = 32; off >= 1; off >>= 1) {
                s0 += __shfl_down(s0, off, 64);
                s1 += __shfl_down(s1, off, 64);
                s2 += __shfl_down(s2, off, 64);
            }
            if (lane == 0) {
                sA[ri] = s0;
                sT[ri] = s1;
                sC[ri] = s2 + bih[grow];
            }
        }
    }
    __syncthreads();   // sA/sT/sC ready

    // ---- wave0 lanes 0-7: gate constants + publish tagged h0 ----
    float apk_r=0, apk_z=0, apk_n=0, atp_r=0, atp_z=0, atp_n=0,
          cvt_r=0, cvt_z=0, cvt_n=0, br=0, bz=0, bn=0, hprev=0;
    if (wv == 0 && lane < JPB) {
        int jj = b*JPB + lane;
        apk_r = sA[lane]; apk_z = sA[8+lane]; apk_n = sA[16+lane];
        atp_r = sT[lane]; atp_z = sT[8+lane]; atp_n = sT[16+lane];
        cvt_r = sC[lane]; cvt_z = sC[8+lane]; cvt_n = sC[16+lane];
        br = bhh[jj]; bz = bhh[jj + Hdim]; bn = bhh[jj + 2*Hdim];
        hprev = smiles[jj];
        // publish h0 with tag 0 (one coalesced 32B wave-store, single line)
        unsigned w0 = (__float_as_uint(hprev) & 0xFFFFFF00u) | 0u;
        __hip_atomic_store(hq + jj, w0,
                           __ATOMIC_RELAXED, __HIP_MEMORY_SCOPE_AGENT);
        if (b == 0 && lane == 0) out[0] = pkdata[0];
    }

    // ================== main recurrence loop ==================
    for (int t = 0; t < Ldim - 1; ++t) {
        const int pr_ = t & 1;
        const unsigned* hin = hq + pr_ * Hdim;
        const unsigned tt = (unsigned)t & 0xFFu;

        // ---- poll: ONE 8B load = detect AND payload; s_sleep backoff ----
        u64 q;
        for (;;) {
            q = __hip_atomic_load((const u64*)(hin + i0),
                                  __ATOMIC_RELAXED, __HIP_MEMORY_SCOPE_AGENT);
            if (((unsigned)q & 0xFFu) == tt &&
                ((unsigned)(q >> 32) & 0xFFu) == tt) break;
            __builtin_amdgcn_s_sleep(1);   // ~64 cyc backoff: kill spin storm
        }
        float h0 = __uint_as_float((unsigned)q         & 0xFFFFFF00u);
        float h1 = __uint_as_float((unsigned)(q >> 32) & 0xFFFFFF00u);
        sh_h[i0]     = h0;
        sh_h[i0 + 1] = h1;

        // local pred partial (pred_{t-1} = W_out . h_t + b_out)
        float wpart = wo0*h0 + wo1*h1;
        #pragma unroll
        for (int off = 32; off >= 1; off >>= 1) wpart += __shfl_down(wpart, off, 64);
        if (lane == 0) swp[pr_][wv] = wpart;
        __syncthreads();                         // B1: h staged

        // ---- dots: 3 gate rows x 16 columns per thread, from LDS ----
        float prd = 0.f, pzd = 0.f, pnd = 0.f;
        #pragma unroll
        for (int c = 0; c < 4; ++c) {
            float4 hv4 = *(const float4*)(sh_h + c*512 + k*4);
            prd += w[0][c].x*hv4.x + w[0][c].y*hv4.y + w[0][c].z*hv4.z + w[0][c].w*hv4.w;
            pzd += w[1][c].x*hv4.x + w[1][c].y*hv4.y + w[1][c].z*hv4.z + w[1][c].w*hv4.w;
            pnd += w[2][c].x*hv4.x + w[2][c].y*hv4.y + w[2][c].z*hv4.z + w[2][c].w*hv4.w;
        }
        #pragma unroll
        for (int off = 32; off >= 1; off >>= 1) {
            prd += __shfl_down(prd, off, 64);
            pzd += __shfl_down(pzd, off, 64);
            pnd += __shfl_down(pnd, off, 64);
        }
        if (lane == 0) { sred[wv][0] = prd; sred[wv][1] = pzd; sred[wv][2] = pnd; }
        __syncthreads();                         // B2: sred ready

        // ---- wave 0: pred, pk, gates, publish FIRST, then out[t] ----
        if (wv == 0) {
            float s = (lane < 16) ? swp[pr_][lane] : 0.f;
            s += __shfl_down(s, 8, 64);
            s += __shfl_down(s, 4, 64);
            s += __shfl_down(s, 2, 64);
            s += __shfl_down(s, 1, 64);
            float pred = __shfl(s, 0) + bo;      // pred_{t-1}
            float pk = (t == 0) ? s_pkd[0] : ((s_tf[t] == 1) ? pred : s_pkd[t]);
            if (lane < JPB) {
                float dotr = sred[2*lane][0] + sred[2*lane+1][0];
                float dotz = sred[2*lane][1] + sred[2*lane+1][1];
                float dotn = sred[2*lane][2] + sred[2*lane+1][2];
                float tp  = s_tp[t];
                float gr  = apk_r*pk + atp_r*tp + cvt_r + dotr + br;
                float gz  = apk_z*pk + atp_z*tp + cvt_z + dotz + bz;
                float gin = apk_n*pk + atp_n*tp + cvt_n;
                float r = 1.0f / (1.0f + expf(-gr));
                float z = 1.0f / (1.0f + expf(-gz));
                float n = tanhf(gin + r*(dotn + bn));
                float hvnew = (1.0f - z)*n + z*hprev;
                hprev = hvnew;
                unsigned wpk = (__float_as_uint(hvnew) & 0xFFFFFF00u)
                             | ((unsigned)(t + 1) & 0xFFu);
                __hip_atomic_store(hq + (pr_^1)*Hdim + b*JPB + lane, wpk,
                                   __ATOMIC_RELAXED, __HIP_MEMORY_SCOPE_AGENT);
            }
            if (b == 0 && lane == 0 && t > 0) out[t] = pred;  // off critical path
        }
    }

    // ---- final: only block 0 polls h_255 and writes out[255] ----
    if (b == 0) {
        const unsigned* hin = hq + ((Ldim - 1) & 1) * Hdim;
        const unsigned tt = (unsigned)(Ldim - 1) & 0xFFu;
        u64 q;
        for (;;) {
            q = __hip_atomic_load((const u64*)(hin + i0),
                                  __ATOMIC_RELAXED, __HIP_MEMORY_SCOPE_AGENT);
            if (((unsigned)q & 0xFFu) == tt &&
                ((unsigned)(q >> 32) & 0xFFu) == tt) break;
            __builtin_amdgcn_s_sleep(1);
        }
        float h0 = __uint_as_float((unsigned)q         & 0xFFFFFF00u);
        float h1 = __uint_as_float((unsigned)(q >> 32) & 0xFFFFFF00u);
        float wpart = wo0*h0 + wo1*h1;
        #pragma unroll
        for (int off = 32; off >= 1; off >>= 1) wpart += __shfl_down(wpart, off, 64);
        if (lane == 0) swp[1][wv] = wpart;
        __syncthreads();
        if (wv == 0) {
            float s = (lane < 16) ? swp[1][lane] : 0.f;
            s += __shfl_down(s, 8, 64);
            s += __shfl_down(s, 4, 64);
            s += __shfl_down(s, 2, 64);
            s += __shfl_down(s, 1, 64);
            if (lane == 0) out[Ldim - 1] = s + bo;
        }
    }
}

extern "C" void kernel_launch(void* const* d_in, const int* in_sizes, int n_in,
                              void* d_out, int out_size, void* d_ws, size_t ws_size,
                              hipStream_t stream)
{
    const float* tps    = (const float*)d_in[0];   // timepoints (256,1)
    const float* pkdata = (const float*)d_in[1];   // pk_data (256,1)
    // d_in[2] = input_len (unused, static 256)
    const int*   pat    = (const int*)  d_in[3];   // emb_patient
    const float* route  = (const float*)d_in[4];   // drug_route (1,)
    const float* dose   = (const float*)d_in[5];   // dose (1,)
    const float* smiles = (const float*)d_in[6];   // (1, 2048)
    const int*   tfm    = (const int*)  d_in[7];   // tf_mask (256,)
    const float* emb    = (const float*)d_in[8];   // emb_table (8,3)
    const float* Wp     = (const float*)d_in[9];   // W_pre (2048,7)
    const float* bpre   = (const float*)d_in[10];  // b_pre (2048,)
    const float* Wih    = (const float*)d_in[11];  // W_ih (6144,2048)
    const float* Whh    = (const float*)d_in[12];  // W_hh (6144,2048)
    const float* bih    = (const float*)d_in[13];  // b_ih (6144,)
    const float* bhh    = (const float*)d_in[14];  // b_hh (6144,)
    const float* Wout   = (const float*)d_in[15];  // W_out (1,2048)
    const float* bout   = (const float*)d_in[16];  // b_out (1,)
    float* out = (float*)d_out;
    float* ws  = (float*)d_ws;

    hipLaunchKernelGGL(gru_all, dim3(NBLK), dim3(TPB), 0, stream,
                       Whh, bhh, Wout, bout, tps, pkdata, tfm, smiles,
                       Wp, bpre, Wih, bih, dose, route, emb, pat, ws, out);
}

// Round 12
// 1010.514 us; speedup vs baseline: 1.2055x; 1.0255x over previous
//
#include <hip/hip_runtime.h>
#include <math.h>

#define Hdim 2048
#define Ldim 256
#define NBLK 256
#define TPB  1024
#define JPB  8      // h-elements per block (Hdim / NBLK)
#define NREP 8      // replicas of the published h (consumers shard by b&7)

typedef unsigned long long u64;

// workspace: packed replicated h buffer: [parity][replica][2048] u32 words.
// word = (f32 bits & 0xFFFFFF00) | step_tag8  — tag rides in the mantissa
// low byte (<=3e-5 relative perturbation). Detect = equality with t.
// Harness poisons ws with 0xAA -> tag byte 0xAA, never equals live tags
// before first write; stale slots hold tag t-2 != t. Race-free (2-phase:
// wave0 publishes only after B2, which proves all waves passed B1 of this
// step, i.e. everyone is done reading the parity being overwritten).
#define WS_HP 0

// ---------------- single fused persistent kernel ----------------------------
// 256 blocks x 1024 threads, 1 block/CU. Block b owns h[j], j = b*8..b*8+7.
// Best-measured protocol (r9, 922 us): minimum-hop tagged payload, 8x
// replicated; producer wave0 emits ONE wave-store covering all replicas;
// consumer block polls only replica b&7 with ONE 8B load = detect+payload.
__global__ __launch_bounds__(TPB, 4) void gru_all(
    const float* __restrict__ Whh,  const float* __restrict__ bhh,
    const float* __restrict__ Wout, const float* __restrict__ bout,
    const float* __restrict__ tps,  const float* __restrict__ pkdata,
    const int*   __restrict__ tf,   const float* __restrict__ smiles,
    const float* __restrict__ Wp,   const float* __restrict__ bpre,
    const float* __restrict__ Wih,  const float* __restrict__ bih,
    const float* __restrict__ dose, const float* __restrict__ route,
    const float* __restrict__ emb,  const int* __restrict__ pat,
    float* __restrict__ ws, float* __restrict__ out)
{
    const int b    = blockIdx.x;
    const int tid  = threadIdx.x;
    const int k    = tid & 127;     // column group within j (dots)
    const int g    = tid >> 7;      // which j this thread's dot serves
    const int wv   = tid >> 6;      // wave id 0..15
    const int lane = tid & 63;
    const int j    = b*JPB + g;
    const int rep  = b & 7;         // this block's poll replica

    __shared__ float su[Hdim];      // u vector (prep only)
    __shared__ float sh_h[Hdim];
    __shared__ float sred[16][3];
    __shared__ float swp[2][16];
    __shared__ float sA[24], sT[24], sC[24];   // APK/ATP/CVT for own 24 rows
    __shared__ float s_tp[Ldim];
    __shared__ float s_pkd[Ldim];
    __shared__ int   s_tf[Ldim];

    unsigned* hq = (unsigned*)(ws + WS_HP);

    // small per-step scalars
    for (int i = tid; i < Ldim; i += TPB) {
        s_tp[i]  = tps[i];
        s_pkd[i] = pkdata[i];
        s_tf[i]  = tf[i];
    }

    // ---- prep A: u[i] = Wp[i,2:7].consts + b_pre[i] into LDS ----
    {
        float d = dose[0], rt = route[0];
        int p = pat[0];
        float e0 = emb[p*3+0], e1 = emb[p*3+1], e2 = emb[p*3+2];
        for (int i = tid; i < Hdim; i += TPB) {
            const float* wr = Wp + i*7;
            su[i] = d*wr[2] + e0*wr[3] + e1*wr[4] + e2*wr[5] + rt*wr[6] + bpre[i];
        }
    }

    // W_hh rows -> registers (48 VGPRs), coalesced float4 loads
    float4 w[3][4];
    #pragma unroll
    for (int r = 0; r < 3; ++r) {
        const float* base = Whh + (size_t)(j + r*Hdim) * Hdim;
        #pragma unroll
        for (int c = 0; c < 4; ++c)
            w[r][c] = *(const float4*)(base + c*512 + k*4);
    }

    // per-thread W_out slice
    const int i0 = tid * 2;
    const float wo0 = Wout[i0], wo1 = Wout[i0 + 1];
    const float bo = bout[0];

    __syncthreads();   // su ready

    // ---- prep B: fold this block's 24 W_ih rows ----
    #pragma unroll
    for (int pass = 0; pass < 2; ++pass) {
        int ri = wv + pass*16;
        if (ri < 24) {
            int grow = (ri >> 3)*Hdim + b*JPB + (ri & 7);
            const float* wr = Wih + (size_t)grow * Hdim;
            float s0 = 0.f, s1 = 0.f, s2 = 0.f;
            #pragma unroll
            for (int c = 0; c < 8; ++c) {
                int col = c*256 + lane*4;
                float4 wv4 = *(const float4*)(wr + col);
                float4 uv4 = *(const float4*)(su + col);
                s0 += wv4.x*Wp[(col+0)*7+0] + wv4.y*Wp[(col+1)*7+0]
                    + wv4.z*Wp[(col+2)*7+0] + wv4.w*Wp[(col+3)*7+0];
                s1 += wv4.x*Wp[(col+0)*7+1] + wv4.y*Wp[(col+1)*7+1]
                    + wv4.z*Wp[(col+2)*7+1] + wv4.w*Wp[(col+3)*7+1];
                s2 += wv4.x*uv4.x + wv4.y*uv4.y + wv4.z*uv4.z + wv4.w*uv4.w;
            }
            #pragma unroll
            for (int off = 32; off >= 1; off >>= 1) {
                s0 += __shfl_down(s0, off, 64);
                s1 += __shfl_down(s1, off, 64);
                s2 += __shfl_down(s2, off, 64);
            }
            if (lane == 0) {
                sA[ri] = s0;
                sT[ri] = s1;
                sC[ri] = s2 + bih[grow];
            }
        }
    }
    __syncthreads();   // sA/sT/sC ready

    // ---- wave0: gate constants (lanes 0-7) + replicated tagged h0 publish --
    float apk_r=0, apk_z=0, apk_n=0, atp_r=0, atp_z=0, atp_n=0,
          cvt_r=0, cvt_z=0, cvt_n=0, br=0, bz=0, bn=0, hprev=0;
    if (wv == 0) {
        float hinit = 0.f;
        if (lane < JPB) {
            int jj = b*JPB + lane;
            apk_r = sA[lane]; apk_z = sA[8+lane]; apk_n = sA[16+lane];
            atp_r = sT[lane]; atp_z = sT[8+lane]; atp_n = sT[16+lane];
            cvt_r = sC[lane]; cvt_z = sC[8+lane]; cvt_n = sC[16+lane];
            br = bhh[jj]; bz = bhh[jj + Hdim]; bn = bhh[jj + 2*Hdim];
            hprev = smiles[jj];
            hinit = hprev;
        }
        // one wave-store covers all 8 replicas: lane -> (rep=lane>>3, lane&7)
        float hv = __shfl(hinit, lane & 7);
        unsigned w0 = (__float_as_uint(hv) & 0xFFFFFF00u);   // tag 0
        __hip_atomic_store(hq + (size_t)(lane >> 3)*Hdim + b*JPB + (lane & 7), w0,
                           __ATOMIC_RELAXED, __HIP_MEMORY_SCOPE_AGENT);
        if (b == 0 && lane == 0) out[0] = pkdata[0];
    }

    // ================== main recurrence loop ==================
    for (int t = 0; t < Ldim - 1; ++t) {
        const int pr_ = t & 1;
        const unsigned* hin = hq + (size_t)(pr_*NREP + rep)*Hdim;
        const unsigned tt = (unsigned)t & 0xFFu;

        // ---- poll: ONE 8B load = detect AND payload (own replica only) ----
        u64 q;
        for (;;) {
            q = __hip_atomic_load((const u64*)(hin + i0),
                                  __ATOMIC_RELAXED, __HIP_MEMORY_SCOPE_AGENT);
            if (((unsigned)q & 0xFFu) == tt &&
                ((unsigned)(q >> 32) & 0xFFu) == tt) break;
        }
        float h0 = __uint_as_float((unsigned)q         & 0xFFFFFF00u);
        float h1 = __uint_as_float((unsigned)(q >> 32) & 0xFFFFFF00u);
        sh_h[i0]     = h0;
        sh_h[i0 + 1] = h1;

        // local pred partial (pred_{t-1} = W_out . h_t + b_out)
        float wpart = wo0*h0 + wo1*h1;
        #pragma unroll
        for (int off = 32; off >= 1; off >>= 1) wpart += __shfl_down(wpart, off, 64);
        if (lane == 0) swp[pr_][wv] = wpart;
        __syncthreads();                         // B1: h staged

        // ---- dots: 3 gate rows x 16 columns per thread, from LDS ----
        float prd = 0.f, pzd = 0.f, pnd = 0.f;
        #pragma unroll
        for (int c = 0; c < 4; ++c) {
            float4 hv4 = *(const float4*)(sh_h + c*512 + k*4);
            prd += w[0][c].x*hv4.x + w[0][c].y*hv4.y + w[0][c].z*hv4.z + w[0][c].w*hv4.w;
            pzd += w[1][c].x*hv4.x + w[1][c].y*hv4.y + w[1][c].z*hv4.z + w[1][c].w*hv4.w;
            pnd += w[2][c].x*hv4.x + w[2][c].y*hv4.y + w[2][c].z*hv4.z + w[2][c].w*hv4.w;
        }
        #pragma unroll
        for (int off = 32; off >= 1; off >>= 1) {
            prd += __shfl_down(prd, off, 64);
            pzd += __shfl_down(pzd, off, 64);
            pnd += __shfl_down(pnd, off, 64);
        }
        if (lane == 0) { sred[wv][0] = prd; sred[wv][1] = pzd; sred[wv][2] = pnd; }
        __syncthreads();                         // B2: sred ready

        // ---- wave 0: pred, pk, gates, replicated publish, THEN out[t] ----
        if (wv == 0) {
            float s = (lane < 16) ? swp[pr_][lane] : 0.f;
            s += __shfl_down(s, 8, 64);
            s += __shfl_down(s, 4, 64);
            s += __shfl_down(s, 2, 64);
            s += __shfl_down(s, 1, 64);
            float pred = __shfl(s, 0) + bo;      // pred_{t-1}
            float pk = (t == 0) ? s_pkd[0] : ((s_tf[t] == 1) ? pred : s_pkd[t]);
            float hvnew = 0.f;
            if (lane < JPB) {
                float dotr = sred[2*lane][0] + sred[2*lane+1][0];
                float dotz = sred[2*lane][1] + sred[2*lane+1][1];
                float dotn = sred[2*lane][2] + sred[2*lane+1][2];
                float tp  = s_tp[t];
                float gr  = apk_r*pk + atp_r*tp + cvt_r + dotr + br;
                float gz  = apk_z*pk + atp_z*tp + cvt_z + dotz + bz;
                float gin = apk_n*pk + atp_n*tp + cvt_n;
                float r = 1.0f / (1.0f + expf(-gr));
                float z = 1.0f / (1.0f + expf(-gz));
                float n = tanhf(gin + r*(dotn + bn));
                hvnew = (1.0f - z)*n + z*hprev;
                hprev = hvnew;
            }
            // one wave-store covers all 8 replicas (critical path)
            float hv = __shfl(hvnew, lane & 7);
            unsigned wpk = (__float_as_uint(hv) & 0xFFFFFF00u)
                         | ((unsigned)(t + 1) & 0xFFu);
            __hip_atomic_store(hq + (size_t)(((pr_^1)*NREP) + (lane >> 3))*Hdim
                                   + b*JPB + (lane & 7), wpk,
                               __ATOMIC_RELAXED, __HIP_MEMORY_SCOPE_AGENT);
            if (b == 0 && lane == 0 && t > 0) out[t] = pred;  // off critical path
        }
    }

    // ---- final: only block 0 polls h_255 (replica 0) and writes out[255] ----
    if (b == 0) {
        const unsigned* hin = hq + (size_t)((((Ldim - 1) & 1))*NREP + 0)*Hdim;
        const unsigned tt = (unsigned)(Ldim - 1) & 0xFFu;
        u64 q;
        for (;;) {
            q = __hip_atomic_load((const u64*)(hin + i0),
                                  __ATOMIC_RELAXED, __HIP_MEMORY_SCOPE_AGENT);
            if (((unsigned)q & 0xFFu) == tt &&
                ((unsigned)(q >> 32) & 0xFFu) == tt) break;
        }
        float h0 = __uint_as_float((unsigned)q         & 0xFFFFFF00u);
        float h1 = __uint_as_float((unsigned)(q >> 32) & 0xFFFFFF00u);
        float wpart = wo0*h0 + wo1*h1;
        #pragma unroll
        for (int off = 32; off >= 1; off >>= 1) wpart += __shfl_down(wpart, off, 64);
        if (lane == 0) swp[1][wv] = wpart;
        __syncthreads();
        if (wv == 0) {
            float s = (lane < 16) ? swp[1][lane] : 0.f;
            s += __shfl_down(s, 8, 64);
            s += __shfl_down(s, 4, 64);
            s += __shfl_down(s, 2, 64);
            s += __shfl_down(s, 1, 64);
            if (lane == 0) out[Ldim - 1] = s + bo;
        }
    }
}

extern "C" void kernel_launch(void* const* d_in, const int* in_sizes, int n_in,
                              void* d_out, int out_size, void* d_ws, size_t ws_size,
                              hipStream_t stream)
{
    const float* tps    = (const float*)d_in[0];   // timepoints (256,1)
    const float* pkdata = (const float*)d_in[1];   // pk_data (256,1)
    // d_in[2] = input_len (unused, static 256)
    const int*   pat    = (const int*)  d_in[3];   // emb_patient
    const float* route  = (const float*)d_in[4];   // drug_route (1,)
    const float* dose   = (const float*)d_in[5];   // dose (1,)
    const float* smiles = (const float*)d_in[6];   // (1, 2048)
    const int*   tfm    = (const int*)  d_in[7];   // tf_mask (256,)
    const float* emb    = (const float*)d_in[8];   // emb_table (8,3)
    const float* Wp     = (const float*)d_in[9];   // W_pre (2048,7)
    const float* bpre   = (const float*)d_in[10];  // b_pre (2048,)
    const float* Wih    = (const float*)d_in[11];  // W_ih (6144,2048)
    const float* Whh    = (const float*)d_in[12];  // W_hh (6144,2048)
    const float* bih    = (const float*)d_in[13];  // b_ih (6144,)
    const float* bhh    = (const float*)d_in[14];  // b_hh (6144,)
    const float* Wout   = (const float*)d_in[15];  // W_out (1,2048)
    const float* bout   = (const float*)d_in[16];  // b_out (1,)
    float* out = (float*)d_out;
    float* ws  = (float*)d_ws;

    hipLaunchKernelGGL(gru_all, dim3(NBLK), dim3(TPB), 0, stream,
                       Whh, bhh, Wout, bout, tps, pkdata, tfm, smiles,
                       Wp, bpre, Wih, bih, dose, route, emb, pat, ws, out);
}